// Round 8
// baseline (270.774 us; speedup 1.0000x reference)
//
#include <hip/hip_runtime.h>
#include <hip/hip_bf16.h>
#include <math.h>

// Problem constants (T=2048, B=2, C=1024, H=16, DK=64)
#define T_SEQ 2048
#define B_SZ 2
#define C_DIM 1024
#define H_HEADS 16
#define DKH 64
#define M_ROWS (T_SEQ * B_SZ)   // 4096 rows in (t,b) order — matches [T,B,C] flat layout

// log2(e)/8: Q projection pre-scale so softmax runs in exp2 domain
#define QSCALE 0.1803368801111204f

typedef __attribute__((ext_vector_type(8))) short bf16x8;   // 8 bf16 = 4 VGPRs (MFMA A/B frag)
typedef __attribute__((ext_vector_type(4))) float f32x4;    // MFMA C/D frag
typedef unsigned short ushort_t;

// ---- helpers ----------------------------------------------------------------

__device__ __forceinline__ ushort_t f2bf(float f) {
    unsigned u = __float_as_uint(f);
    u += 0x7fffu + ((u >> 16) & 1u);
    return (ushort_t)(u >> 16);
}

// packed f32x2 -> bf16x2
__device__ __forceinline__ unsigned pack2bf(float a, float b) {
#if __has_builtin(__builtin_amdgcn_cvt_pk_bf16_f32)
    typedef __attribute__((ext_vector_type(2))) __bf16 bf16x2_t;
    union { bf16x2_t v; unsigned u; } cv;
    cv.v = __builtin_amdgcn_cvt_pk_bf16_f32(a, b);
    return cv.u;
#else
    return (unsigned)f2bf(a) | ((unsigned)f2bf(b) << 16);
#endif
}

__device__ __forceinline__ void async_copy16(const void* g, void* l) {
    __builtin_amdgcn_global_load_lds(
        (const __attribute__((address_space(1))) void*)g,
        (__attribute__((address_space(3))) void*)l, 16, 0, 0);
}

// ---- kernel 1: RoPE on q,k + cast to bf16 (rows t*2+b) ----------------------
__global__ __launch_bounds__(256) void rope_cast_qk(
        const float* __restrict__ q, const float* __restrict__ k,
        ushort_t* __restrict__ qb, ushort_t* __restrict__ kb) {
    int idx  = blockIdx.x * 256 + threadIdx.x;      // [0, T*B*H*32)
    int j    = idx & 31;
    int rest = idx >> 5;                            // t*B*H + b*H + h
    int h    = rest & (H_HEADS - 1);
    int tb   = rest >> 4;                           // t*B + b
    int t    = tb >> 1;
    float inv = exp2f(-(float)j * 0.41524101186092034f);  // 10000^(-j/32)
    float ang = (float)t * inv;
    float s, c;
    sincosf(ang, &s, &c);
    int base = tb * C_DIM + h * DKH + j;
    float q1 = q[base], q2 = q[base + 32];
    float k1 = k[base], k2 = k[base + 32];
    qb[base]      = f2bf(q1 * c - q2 * s);
    qb[base + 32] = f2bf(q2 * c + q1 * s);
    kb[base]      = f2bf(k1 * c - k2 * s);
    kb[base + 32] = f2bf(k2 * c + k1 * s);
}

// ---- kernel 2a: generic fp32 -> bf16 cast (weights) -------------------------
__global__ __launch_bounds__(256) void cast_bf16(
        const float* __restrict__ in, ushort_t* __restrict__ out, int n4) {
    int i = blockIdx.x * 256 + threadIdx.x;
    if (i < n4) {
        float4 v = reinterpret_cast<const float4*>(in)[i];
        ushort4 o;
        o.x = f2bf(v.x); o.y = f2bf(v.y); o.z = f2bf(v.z); o.w = f2bf(v.w);
        reinterpret_cast<ushort4*>(out)[i] = o;
    }
}

// ---- kernel 2b: value cast with row de-interleave: out row = b*T+t ----------
__global__ __launch_bounds__(256) void cast_value_perm(
        const float* __restrict__ in, ushort_t* __restrict__ out) {
    int i   = blockIdx.x * 256 + threadIdx.x;   // float4 index over [4096][256]
    int c4  = i & 255;
    int row = i >> 8;                           // b*2048 + t
    int b   = row >> 11, t = row & 2047;
    float4 v = reinterpret_cast<const float4*>(in)[(t * 2 + b) * 256 + c4];
    ushort4 o;
    o.x = f2bf(v.x); o.y = f2bf(v.y); o.z = f2bf(v.z); o.w = f2bf(v.w);
    reinterpret_cast<ushort4*>(out)[i] = o;
}

// ---- kernel 3: NT GEMM  (verified r6 512-thread version, unchanged) ---------
template <bool BF16_OUT, bool BIAS_ROW>
__global__ __launch_bounds__(512) void gemm_nt(
        const ushort_t* __restrict__ A, const ushort_t* __restrict__ W,
        const float* __restrict__ bias, void* __restrict__ Cout,
        int M, int N, int K, float scale) {
    __shared__ ushort_t As[128 * 64];
    __shared__ ushort_t Bs[128 * 64];
    const int tid  = threadIdx.x;
    const int lane = tid & 63;
    const int w    = tid >> 6;         // 0..7
    const int wr   = w >> 1;           // 0..3 -> 32-row block
    const int wc   = w & 1;            // 0..1 -> 64-col block
    const int m16  = lane & 15, quad = lane >> 4;
    const int r8   = lane >> 3, c8 = lane & 7;
    const int clog = c8 ^ r8;
    const int rowBase = blockIdx.y * 128;
    const int colBase = blockIdx.x * 128;

    f32x4 acc[2][4];
#pragma unroll
    for (int i = 0; i < 2; i++)
#pragma unroll
        for (int j = 0; j < 4; j++) acc[i][j] = (f32x4){0.f, 0.f, 0.f, 0.f};

    for (int kt = 0; kt < K; kt += 64) {
        __syncthreads();
#pragma unroll
        for (int i = 0; i < 2; ++i) {
            int R = w * 16 + i * 8;
            async_copy16(A + (size_t)(rowBase + R + r8) * K + kt + clog * 8,
                         &As[R * 64]);
            async_copy16(W + (size_t)(colBase + R + r8) * K + kt + clog * 8,
                         &Bs[R * 64]);
        }
        __syncthreads();
#pragma unroll
        for (int ks = 0; ks < 2; ++ks) {
            bf16x8 af[2], bfr[4];
            int lc = ks * 4 + quad;
#pragma unroll
            for (int mi = 0; mi < 2; mi++) {
                int R = wr * 32 + mi * 16 + m16;
                af[mi] = *reinterpret_cast<const bf16x8*>(
                    &As[R * 64 + ((lc ^ (R & 7)) << 3)]);
            }
#pragma unroll
            for (int ni = 0; ni < 4; ni++) {
                int R = wc * 64 + ni * 16 + m16;
                bfr[ni] = *reinterpret_cast<const bf16x8*>(
                    &Bs[R * 64 + ((lc ^ (R & 7)) << 3)]);
            }
#pragma unroll
            for (int mi = 0; mi < 2; mi++)
#pragma unroll
                for (int ni = 0; ni < 4; ni++)
                    acc[mi][ni] = __builtin_amdgcn_mfma_f32_16x16x32_bf16(
                        af[mi], bfr[ni], acc[mi][ni], 0, 0, 0);
        }
    }
#pragma unroll
    for (int mi = 0; mi < 2; mi++)
#pragma unroll
        for (int ni = 0; ni < 4; ni++)
#pragma unroll
            for (int r = 0; r < 4; r++) {
                int row = rowBase + wr * 32 + mi * 16 + quad * 4 + r;
                int col = colBase + wc * 64 + ni * 16 + m16;
                float v = (acc[mi][ni][r] + (BIAS_ROW ? bias[row] : bias[col])) * scale;
                if (BF16_OUT)
                    ((ushort_t*)Cout)[(size_t)row * N + col] = f2bf(v);
                else
                    ((float*)Cout)[(size_t)row * N + col] = v;
            }
}

// ---- kernel 4: flash attention, key-owned waves, barrier-free k-loop --------
// Wave w owns keys [kt+w*32, +32) x ALL 64 q. Q B-frags (64 q x 64 dk) are
// register-resident (32 VGPRs). Staging is wave-private (each wave DMAs only
// its own K rows / V^T cols), so the k-loop has NO __syncthreads — waves
// self-pace on s_waitcnt vmcnt(0). P overlays the wave's own Kt quarter.
// Per-wave partial l and O^T (64x64) are reduced across waves in the epilogue.
// r8 fix: __syncthreads() BEFORE the epilogue O-exchange — exch overlays all
// waves' staging quarters, so every wave must have exited the k-loop first
// (r7's NaN: wave 0's exch writes clobbered wave 1's live K tile).
__global__ __launch_bounds__(256) void attn(
        const ushort_t* __restrict__ Qp, const ushort_t* __restrict__ Kp,
        const ushort_t* __restrict__ VTg, ushort_t* __restrict__ X) {
    __shared__ char smem[40960];
    ushort_t* Qt = (ushort_t*)smem;            // [64 q][64 dk]        8 KB
    char*  KtC   = smem + 8192;                // wave w: [32 key][64 dk] @ +w*4096
    char*  VTC   = smem + 24576;               // wave w: [64 dk][32 key] @ +w*4096
    float* exch  = (float*)(smem + 8192);      // epilogue O-exchange (32 KB)
    float* lbuf  = (float*)smem;               // epilogue l-exchange (1 KB, in Qt)

    const int tid  = threadIdx.x;
    const int lane = tid & 63;
    const int w    = tid >> 6;
    const int m16  = lane & 15, quad = lane >> 4;
    const int r8   = lane >> 3, c8 = lane & 7;
    const int clog = c8 ^ r8;

    // XCD-locality swizzle (bijection on 1024 block ids)
    const int lid   = blockIdx.x + blockIdx.y * 32;
    const int jj    = lid >> 3;
    const int pair  = (lid & 7) * 4 + (jj >> 5);   // b*H + h, constant per XCD group
    const int qBase = (jj & 31) * 64;
    const int b = pair >> 4, h = pair & 15;

    // hoisted loop-invariant LDS byte offsets
    const int ofA = m16 * 128 + ((quad ^ (m16 & 7)) << 4);        // ks=0, 128B rows
    const int ofB = m16 * 128 + (((4 + quad) ^ (m16 & 7)) << 4);  // ks=1
    const int fro = m16 * 64 + ((quad ^ (m16 & 3)) << 4);         // pf/vf, 64B rows
    int pw0[2];   // P write offsets (per kt_i), + ni*1024 at use site
#pragma unroll
    for (int kt_i = 0; kt_i < 2; kt_i++)
        pw0[kt_i] = m16 * 64 + ((((kt_i * 2 + (quad >> 1)) ^ (m16 & 3))) << 4) + (quad & 1) * 8;
    char* PwC = KtC + w * 4096;     // P overlay on wave's own Kt quarter

    // ---- prologue: stage Q tile [64 q][64 dk], load ALL 64 q B-frags --------
#pragma unroll
    for (int i = 0; i < 2; ++i) {
        int R = w * 16 + i * 8;
        async_copy16(Qp + (size_t)((qBase + R + r8) * 2 + b) * C_DIM + h * DKH + clog * 8,
                     &Qt[R * 64]);
    }
    __syncthreads();
    bf16x8 aq[4][2];   // aq[ni][ks]: B-frag for q = ni*16 + (lane&15)
#pragma unroll
    for (int ni = 0; ni < 4; ni++) {
        aq[ni][0] = *reinterpret_cast<const bf16x8*>((const char*)Qt + ni * 2048 + ofA);
        aq[ni][1] = *reinterpret_cast<const bf16x8*>((const char*)Qt + ni * 2048 + ofB);
    }
    asm volatile("s_waitcnt lgkmcnt(0)" ::: "memory");
    __syncthreads();

    float lrun[4] = {0.f, 0.f, 0.f, 0.f};   // partial l: q = ni*16+m16, wave's keys
    f32x4 o[4][4];                           // O^T partial: [dk=mi*16+quad*4+r][q=ni*16+m16]
#pragma unroll
    for (int mi = 0; mi < 4; mi++)
#pragma unroll
        for (int ni = 0; ni < 4; ni++) o[mi][ni] = (f32x4){0.f, 0.f, 0.f, 0.f};

    // ---- barrier-free main loop --------------------------------------------
    for (int kt = 0; kt < T_SEQ; kt += 128) {
        // drain own LDS ops (P writes / frag reads) before DMA may overwrite
        asm volatile("s_waitcnt lgkmcnt(0)" ::: "memory");
        // wave-private staging: K rows [kt+w*32, +32) -> KtC quarter
#pragma unroll
        for (int i = 0; i < 4; ++i) {
            int key = kt + w * 32 + i * 8 + r8;
            async_copy16(Kp + (size_t)(key * 2 + b) * C_DIM + h * DKH + clog * 8,
                         KtC + w * 4096 + i * 1024);
        }
        // wave-private staging: V^T [64 dk][keys kt+w*32..+31] -> VTC quarter
#pragma unroll
        for (int i = 0; i < 4; ++i) {
            int dkr = i * 16 + (lane >> 2);
            int lc  = (lane & 3) ^ ((lane >> 2) & 3);
            async_copy16(VTg + (size_t)(h * DKH + dkr) * M_ROWS + b * T_SEQ + kt + w * 32 + lc * 8,
                         VTC + w * 4096 + i * 1024);
        }
        asm volatile("s_waitcnt vmcnt(0)" ::: "memory");
        __builtin_amdgcn_sched_barrier(0);

        // S^T = K·Q^T over wave's 32 keys x 64 q (log2 domain)
        f32x4 s[2][4];
#pragma unroll
        for (int kt_i = 0; kt_i < 2; kt_i++) {
#pragma unroll
            for (int ni = 0; ni < 4; ni++) s[kt_i][ni] = (f32x4){0.f, 0.f, 0.f, 0.f};
            bf16x8 kf0 = *reinterpret_cast<const bf16x8*>(KtC + w * 4096 + kt_i * 2048 + ofA);
            bf16x8 kf1 = *reinterpret_cast<const bf16x8*>(KtC + w * 4096 + kt_i * 2048 + ofB);
#pragma unroll
            for (int ni = 0; ni < 4; ni++) {
                s[kt_i][ni] = __builtin_amdgcn_mfma_f32_16x16x32_bf16(kf0, aq[ni][0], s[kt_i][ni], 0, 0, 0);
                s[kt_i][ni] = __builtin_amdgcn_mfma_f32_16x16x32_bf16(kf1, aq[ni][1], s[kt_i][ni], 0, 0, 0);
            }
        }

        // p = exp2(s); accumulate l; write P (bf16) into wave-private overlay
#pragma unroll
        for (int kt_i = 0; kt_i < 2; kt_i++)
#pragma unroll
            for (int ni = 0; ni < 4; ni++) {
                float p0 = __builtin_amdgcn_exp2f(s[kt_i][ni][0]);
                float p1 = __builtin_amdgcn_exp2f(s[kt_i][ni][1]);
                float p2 = __builtin_amdgcn_exp2f(s[kt_i][ni][2]);
                float p3 = __builtin_amdgcn_exp2f(s[kt_i][ni][3]);
                lrun[ni] += (p0 + p1) + (p2 + p3);
                uint2 pv;
                pv.x = pack2bf(p0, p1);
                pv.y = pack2bf(p2, p3);
                *reinterpret_cast<uint2*>(PwC + ni * 1024 + pw0[kt_i]) = pv;
            }
        asm volatile("s_waitcnt lgkmcnt(0)" ::: "memory");

        // O^T += V^T·P^T  (K=32 covers the wave's full key range in one MFMA)
        bf16x8 pf[4];
#pragma unroll
        for (int ni = 0; ni < 4; ni++)
            pf[ni] = *reinterpret_cast<const bf16x8*>(PwC + ni * 1024 + fro);
#pragma unroll
        for (int mi = 0; mi < 4; mi++) {
            bf16x8 vf = *reinterpret_cast<const bf16x8*>(VTC + w * 4096 + mi * 1024 + fro);
#pragma unroll
            for (int ni = 0; ni < 4; ni++)
                o[mi][ni] = __builtin_amdgcn_mfma_f32_16x16x32_bf16(vf, pf[ni], o[mi][ni], 0, 0, 0);
        }
    }

    // ---- epilogue: cross-wave l and O reduction -----------------------------
    // l: reduce quads (keys within wave), publish per-wave partials
#pragma unroll
    for (int ni = 0; ni < 4; ni++) {
        lrun[ni] += __shfl_xor(lrun[ni], 16);
        lrun[ni] += __shfl_xor(lrun[ni], 32);
    }
    float lv = quad == 0 ? lrun[0] : quad == 1 ? lrun[1] : quad == 2 ? lrun[2] : lrun[3];
    lbuf[w * 64 + quad * 16 + m16] = lv;   // Qt region: dead since prologue, no race

    // r8 FIX: all waves must exit the k-loop before exch (overlaying their
    // staging quarters) is written.
    __syncthreads();

    // O exchange in 2 rounds over the now-dead Kt+VT region (32 KB)
#pragma unroll
    for (int rnd = 0; rnd < 2; rnd++) {
        if (rnd) __syncthreads();    // protect region reuse between rounds
        // write this wave's partials for dk tiles {2rnd, 2rnd+1}
#pragma unroll
        for (int t2 = 0; t2 < 2; t2++) {
            int mi = 2 * rnd + t2;
#pragma unroll
            for (int ni = 0; ni < 4; ni++) {
                int q = ni * 16 + m16;
                int cw = t2 * 4 + quad;                 // chunk16 within 32-dk row
                *reinterpret_cast<f32x4*>(
                    &exch[w * 2048 + q * 32 + ((cw ^ (q & 7)) << 2)]) = o[mi][ni];
            }
        }
        __syncthreads();
        // sum 4 wave slots, normalize, store X (thread = (q, chunk))
        int q = tid >> 2;
        float lsum = lbuf[q] + lbuf[64 + q] + lbuf[128 + q] + lbuf[192 + q];
        float invl = 1.0f / lsum;
#pragma unroll
        for (int half = 0; half < 2; half++) {
            int c = (tid & 3) + 4 * half;
            int off = q * 32 + (((c ^ (q & 7))) << 2);
            f32x4 v = *reinterpret_cast<const f32x4*>(&exch[off]);
            f32x4 v1 = *reinterpret_cast<const f32x4*>(&exch[2048 + off]);
            f32x4 v2 = *reinterpret_cast<const f32x4*>(&exch[4096 + off]);
            f32x4 v3 = *reinterpret_cast<const f32x4*>(&exch[6144 + off]);
            v = v + v1 + v2 + v3;
            uint2 pk;
            pk.x = pack2bf(v[0] * invl, v[1] * invl);
            pk.y = pack2bf(v[2] * invl, v[3] * invl);
            int t = qBase + q;
            *reinterpret_cast<uint2*>(
                &X[(size_t)(t * 2 + b) * C_DIM + h * DKH + rnd * 32 + c * 4]) = pk;
        }
    }
}

// ---- launch -----------------------------------------------------------------
extern "C" void kernel_launch(void* const* d_in, const int* in_sizes, int n_in,
                              void* d_out, int out_size, void* d_ws, size_t ws_size,
                              hipStream_t stream) {
    const float* query = (const float*)d_in[0];
    const float* key   = (const float*)d_in[1];
    const float* value = (const float*)d_in[2];
    const float* Wq = (const float*)d_in[3];
    const float* bq = (const float*)d_in[4];
    const float* Wk = (const float*)d_in[5];
    const float* bk = (const float*)d_in[6];
    const float* Wv = (const float*)d_in[7];
    const float* bv = (const float*)d_in[8];
    const float* Wo = (const float*)d_in[9];
    const float* bo = (const float*)d_in[10];
    float* out = (float*)d_out;

    ushort_t* qb  = (ushort_t*)d_ws;                    // [4096][1024] rows t*2+b
    ushort_t* kb  = qb  + (size_t)M_ROWS * C_DIM;
    ushort_t* vb2 = kb  + (size_t)M_ROWS * C_DIM;       // [4096][1024] rows b*T+t
    ushort_t* Wqb = vb2 + (size_t)M_ROWS * C_DIM;
    ushort_t* Wkb = Wqb + (size_t)C_DIM * C_DIM;
    ushort_t* Wvb = Wkb + (size_t)C_DIM * C_DIM;
    ushort_t* Wob = Wvb + (size_t)C_DIM * C_DIM;
    ushort_t* Qp  = Wob + (size_t)C_DIM * C_DIM;        // [4096][1024] rows t*2+b
    ushort_t* Kp  = Qp  + (size_t)M_ROWS * C_DIM;
    ushort_t* VTg = Kp  + (size_t)M_ROWS * C_DIM;       // [1024][4096] cols b*T+t
    ushort_t* Xb  = VTg + (size_t)M_ROWS * C_DIM;       // [4096][1024] rows t*2+b

    // 1) RoPE + casts
    rope_cast_qk<<<(T_SEQ * B_SZ * H_HEADS * 32) / 256, 256, 0, stream>>>(query, key, qb, kb);
    cast_value_perm<<<(M_ROWS * C_DIM / 4) / 256, 256, 0, stream>>>(value, vb2);
    cast_bf16<<<(C_DIM * C_DIM / 4) / 256, 256, 0, stream>>>(Wq, Wqb, C_DIM * C_DIM / 4);
    cast_bf16<<<(C_DIM * C_DIM / 4) / 256, 256, 0, stream>>>(Wk, Wkb, C_DIM * C_DIM / 4);
    cast_bf16<<<(C_DIM * C_DIM / 4) / 256, 256, 0, stream>>>(Wv, Wvb, C_DIM * C_DIM / 4);
    cast_bf16<<<(C_DIM * C_DIM / 4) / 256, 256, 0, stream>>>(Wo, Wob, C_DIM * C_DIM / 4);

    // 2) projections: Q pre-scaled into log2 domain (QSCALE); K natural; V swapped => V^T
    dim3 gg(C_DIM / 128, M_ROWS / 128);
    gemm_nt<true, false><<<gg, 512, 0, stream>>>(qb, Wqb, bq, Qp, M_ROWS, C_DIM, C_DIM, QSCALE);
    gemm_nt<true, false><<<gg, 512, 0, stream>>>(kb, Wkb, bk, Kp, M_ROWS, C_DIM, C_DIM, 1.0f);
    dim3 gv(M_ROWS / 128, C_DIM / 128);
    gemm_nt<true, true><<<gv, 512, 0, stream>>>(Wvb, vb2, bv, VTg, C_DIM, M_ROWS, C_DIM, 1.0f);

    // 3) flash attention (key-owned waves, barrier-free k-loop)
    attn<<<dim3(T_SEQ / 64, B_SZ * H_HEADS), 256, 0, stream>>>(Qp, Kp, VTg, Xb);

    // 4) output projection -> fp32 d_out
    gemm_nt<false, false><<<gg, 512, 0, stream>>>(Xb, Wob, bo, (void*)out, M_ROWS, C_DIM, C_DIM, 1.0f);
}

// Round 9
// 258.367 us; speedup vs baseline: 1.0480x; 1.0480x over previous
//
#include <hip/hip_runtime.h>
#include <hip/hip_bf16.h>
#include <math.h>

// Problem constants (T=2048, B=2, C=1024, H=16, DK=64)
#define T_SEQ 2048
#define B_SZ 2
#define C_DIM 1024
#define H_HEADS 16
#define DKH 64
#define M_ROWS (T_SEQ * B_SZ)   // 4096 rows in (t,b) order — matches [T,B,C] flat layout

// log2(e)/8: Q projection pre-scale so softmax runs in exp2 domain
#define QSCALE 0.1803368801111204f

typedef __attribute__((ext_vector_type(8))) short bf16x8;   // 8 bf16 = 4 VGPRs (MFMA A/B frag)
typedef __attribute__((ext_vector_type(4))) float f32x4;    // MFMA C/D frag
typedef unsigned short ushort_t;

// ---- helpers ----------------------------------------------------------------

__device__ __forceinline__ ushort_t f2bf(float f) {
    unsigned u = __float_as_uint(f);
    u += 0x7fffu + ((u >> 16) & 1u);
    return (ushort_t)(u >> 16);
}

// packed f32x2 -> bf16x2
__device__ __forceinline__ unsigned pack2bf(float a, float b) {
#if __has_builtin(__builtin_amdgcn_cvt_pk_bf16_f32)
    typedef __attribute__((ext_vector_type(2))) __bf16 bf16x2_t;
    union { bf16x2_t v; unsigned u; } cv;
    cv.v = __builtin_amdgcn_cvt_pk_bf16_f32(a, b);
    return cv.u;
#else
    return (unsigned)f2bf(a) | ((unsigned)f2bf(b) << 16);
#endif
}

__device__ __forceinline__ void async_copy16(const void* g, void* l) {
    __builtin_amdgcn_global_load_lds(
        (const __attribute__((address_space(1))) void*)g,
        (__attribute__((address_space(3))) void*)l, 16, 0, 0);
}

// ---- kernel 1: RoPE on q,k + cast to bf16 (rows t*2+b) ----------------------
__global__ __launch_bounds__(256) void rope_cast_qk(
        const float* __restrict__ q, const float* __restrict__ k,
        ushort_t* __restrict__ qb, ushort_t* __restrict__ kb) {
    int idx  = blockIdx.x * 256 + threadIdx.x;      // [0, T*B*H*32)
    int j    = idx & 31;
    int rest = idx >> 5;                            // t*B*H + b*H + h
    int h    = rest & (H_HEADS - 1);
    int tb   = rest >> 4;                           // t*B + b
    int t    = tb >> 1;
    float inv = exp2f(-(float)j * 0.41524101186092034f);  // 10000^(-j/32)
    float ang = (float)t * inv;
    float s, c;
    sincosf(ang, &s, &c);
    int base = tb * C_DIM + h * DKH + j;
    float q1 = q[base], q2 = q[base + 32];
    float k1 = k[base], k2 = k[base + 32];
    qb[base]      = f2bf(q1 * c - q2 * s);
    qb[base + 32] = f2bf(q2 * c + q1 * s);
    kb[base]      = f2bf(k1 * c - k2 * s);
    kb[base + 32] = f2bf(k2 * c + k1 * s);
}

// ---- kernel 2a: generic fp32 -> bf16 cast (weights) -------------------------
__global__ __launch_bounds__(256) void cast_bf16(
        const float* __restrict__ in, ushort_t* __restrict__ out, int n4) {
    int i = blockIdx.x * 256 + threadIdx.x;
    if (i < n4) {
        float4 v = reinterpret_cast<const float4*>(in)[i];
        ushort4 o;
        o.x = f2bf(v.x); o.y = f2bf(v.y); o.z = f2bf(v.z); o.w = f2bf(v.w);
        reinterpret_cast<ushort4*>(out)[i] = o;
    }
}

// ---- kernel 2b: value cast with row de-interleave: out row = b*T+t ----------
__global__ __launch_bounds__(256) void cast_value_perm(
        const float* __restrict__ in, ushort_t* __restrict__ out) {
    int i   = blockIdx.x * 256 + threadIdx.x;   // float4 index over [4096][256]
    int c4  = i & 255;
    int row = i >> 8;                           // b*2048 + t
    int b   = row >> 11, t = row & 2047;
    float4 v = reinterpret_cast<const float4*>(in)[(t * 2 + b) * 256 + c4];
    ushort4 o;
    o.x = f2bf(v.x); o.y = f2bf(v.y); o.z = f2bf(v.z); o.w = f2bf(v.w);
    reinterpret_cast<ushort4*>(out)[i] = o;
}

// ---- kernel 3: NT GEMM, 128x64 tile, 512 thr --------------------------------
// Round-9 change: BM=128, BN=64 => grid doubles to 512 blocks = 2 blocks/CU
// (was 256 = 1/CU; m97-ladder structure needs oversubscription to cover the
// barrier drain). Wave w owns rows [w*16, w*16+16) x all 64 cols: af x1,
// bfr x4, acc x4. LDS 24 KB. Staging/swizzle scheme identical to the verified
// r6 kernel (lane r8 = row&7; phys chunk = logical ^ (row&7)).
template <bool BF16_OUT, bool BIAS_ROW>
__global__ __launch_bounds__(512) void gemm_nt(
        const ushort_t* __restrict__ A, const ushort_t* __restrict__ W,
        const float* __restrict__ bias, void* __restrict__ Cout,
        int M, int N, int K, float scale) {
    __shared__ ushort_t As[128 * 64];
    __shared__ ushort_t Bs[64 * 64];
    const int tid  = threadIdx.x;
    const int lane = tid & 63;
    const int w    = tid >> 6;         // 0..7
    const int m16  = lane & 15, quad = lane >> 4;
    const int r8   = lane >> 3, c8 = lane & 7;
    const int clog = c8 ^ r8;
    const int rowBase = blockIdx.y * 128;
    const int colBase = blockIdx.x * 64;

    f32x4 acc[4];
#pragma unroll
    for (int j = 0; j < 4; j++) acc[j] = (f32x4){0.f, 0.f, 0.f, 0.f};

    for (int kt = 0; kt < K; kt += 64) {
        __syncthreads();
        // As: 128 rows, 8 waves x 2 copies x 8 rows
#pragma unroll
        for (int i = 0; i < 2; ++i) {
            int R = w * 16 + i * 8;
            async_copy16(A + (size_t)(rowBase + R + r8) * K + kt + clog * 8,
                         &As[R * 64]);
        }
        // Bs: 64 rows, 8 waves x 1 copy x 8 rows
        {
            int R = w * 8;
            async_copy16(W + (size_t)(colBase + R + r8) * K + kt + clog * 8,
                         &Bs[R * 64]);
        }
        __syncthreads();
#pragma unroll
        for (int ks = 0; ks < 2; ++ks) {
            int lc = ks * 4 + quad;
            bf16x8 af;
            {
                int R = w * 16 + m16;
                af = *reinterpret_cast<const bf16x8*>(
                    &As[R * 64 + ((lc ^ (R & 7)) << 3)]);
            }
            bf16x8 bfr[4];
#pragma unroll
            for (int ni = 0; ni < 4; ni++) {
                int R = ni * 16 + m16;
                bfr[ni] = *reinterpret_cast<const bf16x8*>(
                    &Bs[R * 64 + ((lc ^ (R & 7)) << 3)]);
            }
#pragma unroll
            for (int ni = 0; ni < 4; ni++)
                acc[ni] = __builtin_amdgcn_mfma_f32_16x16x32_bf16(
                    af, bfr[ni], acc[ni], 0, 0, 0);
        }
    }
#pragma unroll
    for (int ni = 0; ni < 4; ni++)
#pragma unroll
        for (int r = 0; r < 4; r++) {
            int row = rowBase + w * 16 + quad * 4 + r;
            int col = colBase + ni * 16 + m16;
            float v = (acc[ni][r] + (BIAS_ROW ? bias[row] : bias[col])) * scale;
            if (BF16_OUT)
                ((ushort_t*)Cout)[(size_t)row * N + col] = f2bf(v);
            else
                ((float*)Cout)[(size_t)row * N + col] = v;
        }
}

// ---- kernel 4: flash attention (r8 verified version, unchanged) -------------
__global__ __launch_bounds__(256) void attn(
        const ushort_t* __restrict__ Qp, const ushort_t* __restrict__ Kp,
        const ushort_t* __restrict__ VTg, ushort_t* __restrict__ X) {
    __shared__ char smem[40960];
    ushort_t* Qt = (ushort_t*)smem;            // [64 q][64 dk]        8 KB
    char*  KtC   = smem + 8192;                // wave w: [32 key][64 dk] @ +w*4096
    char*  VTC   = smem + 24576;               // wave w: [64 dk][32 key] @ +w*4096
    float* exch  = (float*)(smem + 8192);      // epilogue O-exchange (32 KB)
    float* lbuf  = (float*)smem;               // epilogue l-exchange (1 KB, in Qt)

    const int tid  = threadIdx.x;
    const int lane = tid & 63;
    const int w    = tid >> 6;
    const int m16  = lane & 15, quad = lane >> 4;
    const int r8   = lane >> 3, c8 = lane & 7;
    const int clog = c8 ^ r8;

    // XCD-locality swizzle (bijection on 1024 block ids)
    const int lid   = blockIdx.x + blockIdx.y * 32;
    const int jj    = lid >> 3;
    const int pair  = (lid & 7) * 4 + (jj >> 5);   // b*H + h, constant per XCD group
    const int qBase = (jj & 31) * 64;
    const int b = pair >> 4, h = pair & 15;

    // hoisted loop-invariant LDS byte offsets
    const int ofA = m16 * 128 + ((quad ^ (m16 & 7)) << 4);        // ks=0, 128B rows
    const int ofB = m16 * 128 + (((4 + quad) ^ (m16 & 7)) << 4);  // ks=1
    const int fro = m16 * 64 + ((quad ^ (m16 & 3)) << 4);         // pf/vf, 64B rows
    int pw0[2];
#pragma unroll
    for (int kt_i = 0; kt_i < 2; kt_i++)
        pw0[kt_i] = m16 * 64 + ((((kt_i * 2 + (quad >> 1)) ^ (m16 & 3))) << 4) + (quad & 1) * 8;
    char* PwC = KtC + w * 4096;     // P overlay on wave's own Kt quarter

    // ---- prologue: stage Q tile [64 q][64 dk], load ALL 64 q B-frags --------
#pragma unroll
    for (int i = 0; i < 2; ++i) {
        int R = w * 16 + i * 8;
        async_copy16(Qp + (size_t)((qBase + R + r8) * 2 + b) * C_DIM + h * DKH + clog * 8,
                     &Qt[R * 64]);
    }
    __syncthreads();
    bf16x8 aq[4][2];
#pragma unroll
    for (int ni = 0; ni < 4; ni++) {
        aq[ni][0] = *reinterpret_cast<const bf16x8*>((const char*)Qt + ni * 2048 + ofA);
        aq[ni][1] = *reinterpret_cast<const bf16x8*>((const char*)Qt + ni * 2048 + ofB);
    }
    asm volatile("s_waitcnt lgkmcnt(0)" ::: "memory");
    __syncthreads();

    float lrun[4] = {0.f, 0.f, 0.f, 0.f};
    f32x4 o[4][4];
#pragma unroll
    for (int mi = 0; mi < 4; mi++)
#pragma unroll
        for (int ni = 0; ni < 4; ni++) o[mi][ni] = (f32x4){0.f, 0.f, 0.f, 0.f};

    // ---- barrier-free main loop --------------------------------------------
    for (int kt = 0; kt < T_SEQ; kt += 128) {
        asm volatile("s_waitcnt lgkmcnt(0)" ::: "memory");
#pragma unroll
        for (int i = 0; i < 4; ++i) {
            int key = kt + w * 32 + i * 8 + r8;
            async_copy16(Kp + (size_t)(key * 2 + b) * C_DIM + h * DKH + clog * 8,
                         KtC + w * 4096 + i * 1024);
        }
#pragma unroll
        for (int i = 0; i < 4; ++i) {
            int dkr = i * 16 + (lane >> 2);
            int lc  = (lane & 3) ^ ((lane >> 2) & 3);
            async_copy16(VTg + (size_t)(h * DKH + dkr) * M_ROWS + b * T_SEQ + kt + w * 32 + lc * 8,
                         VTC + w * 4096 + i * 1024);
        }
        asm volatile("s_waitcnt vmcnt(0)" ::: "memory");
        __builtin_amdgcn_sched_barrier(0);

        // S^T = K·Q^T over wave's 32 keys x 64 q (log2 domain)
        f32x4 s[2][4];
#pragma unroll
        for (int kt_i = 0; kt_i < 2; kt_i++) {
#pragma unroll
            for (int ni = 0; ni < 4; ni++) s[kt_i][ni] = (f32x4){0.f, 0.f, 0.f, 0.f};
            bf16x8 kf0 = *reinterpret_cast<const bf16x8*>(KtC + w * 4096 + kt_i * 2048 + ofA);
            bf16x8 kf1 = *reinterpret_cast<const bf16x8*>(KtC + w * 4096 + kt_i * 2048 + ofB);
#pragma unroll
            for (int ni = 0; ni < 4; ni++) {
                s[kt_i][ni] = __builtin_amdgcn_mfma_f32_16x16x32_bf16(kf0, aq[ni][0], s[kt_i][ni], 0, 0, 0);
                s[kt_i][ni] = __builtin_amdgcn_mfma_f32_16x16x32_bf16(kf1, aq[ni][1], s[kt_i][ni], 0, 0, 0);
            }
        }

        // p = exp2(s); accumulate l; write P (bf16) into wave-private overlay
#pragma unroll
        for (int kt_i = 0; kt_i < 2; kt_i++)
#pragma unroll
            for (int ni = 0; ni < 4; ni++) {
                float p0 = __builtin_amdgcn_exp2f(s[kt_i][ni][0]);
                float p1 = __builtin_amdgcn_exp2f(s[kt_i][ni][1]);
                float p2 = __builtin_amdgcn_exp2f(s[kt_i][ni][2]);
                float p3 = __builtin_amdgcn_exp2f(s[kt_i][ni][3]);
                lrun[ni] += (p0 + p1) + (p2 + p3);
                uint2 pv;
                pv.x = pack2bf(p0, p1);
                pv.y = pack2bf(p2, p3);
                *reinterpret_cast<uint2*>(PwC + ni * 1024 + pw0[kt_i]) = pv;
            }
        asm volatile("s_waitcnt lgkmcnt(0)" ::: "memory");

        // O^T += V^T·P^T
        bf16x8 pf[4];
#pragma unroll
        for (int ni = 0; ni < 4; ni++)
            pf[ni] = *reinterpret_cast<const bf16x8*>(PwC + ni * 1024 + fro);
#pragma unroll
        for (int mi = 0; mi < 4; mi++) {
            bf16x8 vf = *reinterpret_cast<const bf16x8*>(VTC + w * 4096 + mi * 1024 + fro);
#pragma unroll
            for (int ni = 0; ni < 4; ni++)
                o[mi][ni] = __builtin_amdgcn_mfma_f32_16x16x32_bf16(vf, pf[ni], o[mi][ni], 0, 0, 0);
        }
    }

    // ---- epilogue: cross-wave l and O reduction -----------------------------
#pragma unroll
    for (int ni = 0; ni < 4; ni++) {
        lrun[ni] += __shfl_xor(lrun[ni], 16);
        lrun[ni] += __shfl_xor(lrun[ni], 32);
    }
    float lv = quad == 0 ? lrun[0] : quad == 1 ? lrun[1] : quad == 2 ? lrun[2] : lrun[3];
    lbuf[w * 64 + quad * 16 + m16] = lv;

    __syncthreads();   // all waves out of k-loop before exch overlays staging

    // O exchange in 2 rounds over the now-dead Kt+VT region (32 KB)
#pragma unroll
    for (int rnd = 0; rnd < 2; rnd++) {
        if (rnd) __syncthreads();
#pragma unroll
        for (int t2 = 0; t2 < 2; t2++) {
            int mi = 2 * rnd + t2;
#pragma unroll
            for (int ni = 0; ni < 4; ni++) {
                int q = ni * 16 + m16;
                int cw = t2 * 4 + quad;
                *reinterpret_cast<f32x4*>(
                    &exch[w * 2048 + q * 32 + ((cw ^ (q & 7)) << 2)]) = o[mi][ni];
            }
        }
        __syncthreads();
        int q = tid >> 2;
        float lsum = lbuf[q] + lbuf[64 + q] + lbuf[128 + q] + lbuf[192 + q];
        float invl = 1.0f / lsum;
#pragma unroll
        for (int half = 0; half < 2; half++) {
            int c = (tid & 3) + 4 * half;
            int off = q * 32 + (((c ^ (q & 7))) << 2);
            f32x4 v = *reinterpret_cast<const f32x4*>(&exch[off]);
            f32x4 v1 = *reinterpret_cast<const f32x4*>(&exch[2048 + off]);
            f32x4 v2 = *reinterpret_cast<const f32x4*>(&exch[4096 + off]);
            f32x4 v3 = *reinterpret_cast<const f32x4*>(&exch[6144 + off]);
            v = v + v1 + v2 + v3;
            uint2 pk;
            pk.x = pack2bf(v[0] * invl, v[1] * invl);
            pk.y = pack2bf(v[2] * invl, v[3] * invl);
            int t = qBase + q;
            *reinterpret_cast<uint2*>(
                &X[(size_t)(t * 2 + b) * C_DIM + h * DKH + rnd * 32 + c * 4]) = pk;
        }
    }
}

// ---- launch -----------------------------------------------------------------
extern "C" void kernel_launch(void* const* d_in, const int* in_sizes, int n_in,
                              void* d_out, int out_size, void* d_ws, size_t ws_size,
                              hipStream_t stream) {
    const float* query = (const float*)d_in[0];
    const float* key   = (const float*)d_in[1];
    const float* value = (const float*)d_in[2];
    const float* Wq = (const float*)d_in[3];
    const float* bq = (const float*)d_in[4];
    const float* Wk = (const float*)d_in[5];
    const float* bk = (const float*)d_in[6];
    const float* Wv = (const float*)d_in[7];
    const float* bv = (const float*)d_in[8];
    const float* Wo = (const float*)d_in[9];
    const float* bo = (const float*)d_in[10];
    float* out = (float*)d_out;

    ushort_t* qb  = (ushort_t*)d_ws;                    // [4096][1024] rows t*2+b
    ushort_t* kb  = qb  + (size_t)M_ROWS * C_DIM;
    ushort_t* vb2 = kb  + (size_t)M_ROWS * C_DIM;       // [4096][1024] rows b*T+t
    ushort_t* Wqb = vb2 + (size_t)M_ROWS * C_DIM;
    ushort_t* Wkb = Wqb + (size_t)C_DIM * C_DIM;
    ushort_t* Wvb = Wkb + (size_t)C_DIM * C_DIM;
    ushort_t* Wob = Wvb + (size_t)C_DIM * C_DIM;
    ushort_t* Qp  = Wob + (size_t)C_DIM * C_DIM;        // [4096][1024] rows t*2+b
    ushort_t* Kp  = Qp  + (size_t)M_ROWS * C_DIM;
    ushort_t* VTg = Kp  + (size_t)M_ROWS * C_DIM;       // [1024][4096] cols b*T+t
    ushort_t* Xb  = VTg + (size_t)M_ROWS * C_DIM;       // [4096][1024] rows t*2+b

    // 1) RoPE + casts
    rope_cast_qk<<<(T_SEQ * B_SZ * H_HEADS * 32) / 256, 256, 0, stream>>>(query, key, qb, kb);
    cast_value_perm<<<(M_ROWS * C_DIM / 4) / 256, 256, 0, stream>>>(value, vb2);
    cast_bf16<<<(C_DIM * C_DIM / 4) / 256, 256, 0, stream>>>(Wq, Wqb, C_DIM * C_DIM / 4);
    cast_bf16<<<(C_DIM * C_DIM / 4) / 256, 256, 0, stream>>>(Wk, Wkb, C_DIM * C_DIM / 4);
    cast_bf16<<<(C_DIM * C_DIM / 4) / 256, 256, 0, stream>>>(Wv, Wvb, C_DIM * C_DIM / 4);
    cast_bf16<<<(C_DIM * C_DIM / 4) / 256, 256, 0, stream>>>(Wo, Wob, C_DIM * C_DIM / 4);

    // 2) projections (128x64 tiles, 512 blocks each = 2/CU)
    dim3 gg(C_DIM / 64, M_ROWS / 128);            // (16, 32)
    gemm_nt<true, false><<<gg, 512, 0, stream>>>(qb, Wqb, bq, Qp, M_ROWS, C_DIM, C_DIM, QSCALE);
    gemm_nt<true, false><<<gg, 512, 0, stream>>>(kb, Wkb, bk, Kp, M_ROWS, C_DIM, C_DIM, 1.0f);
    dim3 gv(M_ROWS / 64, C_DIM / 128);            // (64, 8)
    gemm_nt<true, true><<<gv, 512, 0, stream>>>(Wvb, vb2, bv, VTg, C_DIM, M_ROWS, C_DIM, 1.0f);

    // 3) flash attention (r8 verified, unchanged)
    attn<<<dim3(T_SEQ / 64, B_SZ * H_HEADS), 256, 0, stream>>>(Qp, Kp, VTg, Xb);

    // 4) output projection -> fp32 d_out
    gemm_nt<false, false><<<gg, 512, 0, stream>>>(Xb, Wob, bo, (void*)out, M_ROWS, C_DIM, C_DIM, 1.0f);
}